// Round 1
// baseline (303.021 us; speedup 1.0000x reference)
//
#include <hip/hip_runtime.h>
#include <hip/hip_bf16.h>

// ---------- common ----------
typedef __bf16 bf16x8 __attribute__((ext_vector_type(8)));
typedef float  f32x4  __attribute__((ext_vector_type(4)));

#define GLOAD_LDS16(g, l) \
  __builtin_amdgcn_global_load_lds((const __attribute__((address_space(1))) void*)(g), \
                                   (__attribute__((address_space(3))) void*)(l), 16, 0, 0)

static __device__ __forceinline__ ushort f2bf(float f) {
  union { float f; unsigned u; } x; x.f = f;
  unsigned r = x.u + 0x7fffu + ((x.u >> 16) & 1u);   // RNE
  return (ushort)(r >> 16);
}

// ---------- kernel 1: cast x fp32 -> bf16 ----------
__global__ void cast_x_k(const float4* __restrict__ in, ushort4* __restrict__ out, int n4) {
  int idx = blockIdx.x * 256 + threadIdx.x;
  int stride = gridDim.x * 256;
  for (int i = idx; i < n4; i += stride) {
    float4 v = in[i];
    ushort4 o;
    o.x = f2bf(v.x); o.y = f2bf(v.y); o.z = f2bf(v.z); o.w = f2bf(v.w);
    out[i] = o;
  }
}

// ---------- kernel 2: pack 6 weights into Wt[1408][2048] bf16 (transposed) ----------
// column map: 0-95 a_q | 96-111 a_k | 112-127 a_v | 128-895 b_q | 896-1151 b_k | 1152-1407 b_v
__global__ void pack_wt_k(const float* __restrict__ W0, const float* __restrict__ W1,
                          const float* __restrict__ W2, const float* __restrict__ W3,
                          const float* __restrict__ W4, const float* __restrict__ W5,
                          ushort* __restrict__ Wt) {
  __shared__ ushort tile[64 * 66];
  const int k0 = blockIdx.x * 64, c0 = blockIdx.y * 64;
  const int tid = threadIdx.x;
#pragma unroll
  for (int i = 0; i < 16; ++i) {
    int idx = tid + i * 256;
    int kl = idx >> 6, cl = idx & 63;
    int c = c0 + cl, k = k0 + kl;
    const float* W; int n, lc;
    if (c < 96)       { W = W0; n = 96;  lc = c; }
    else if (c < 112) { W = W1; n = 16;  lc = c - 96; }
    else if (c < 128) { W = W2; n = 16;  lc = c - 112; }
    else if (c < 896) { W = W3; n = 768; lc = c - 128; }
    else if (c < 1152){ W = W4; n = 256; lc = c - 896; }
    else              { W = W5; n = 256; lc = c - 1152; }
    tile[cl * 66 + kl] = f2bf(W[(size_t)k * n + lc]);
  }
  __syncthreads();
#pragma unroll
  for (int i = 0; i < 16; ++i) {
    int idx = tid + i * 256;
    int cl = idx >> 6, kl = idx & 63;
    Wt[(size_t)(c0 + cl) * 2048 + (k0 + kl)] = tile[cl * 66 + kl];
  }
}

// ---------- kernel 3: GEMM  Y[8192][1408] = Xbf[8192][2048] @ Wt[1408][2048]^T ----------
// 128x128 tile, BK=32, 4 waves (2x2), mfma_f32_16x16x32_bf16.
// LDS layout: A rows / B cols as [idx][32] bf16, 16B slot s XOR-swizzled with ((row>>1)&3),
// applied both on the global staging source and on the ds_read side (rule 21).
__global__ __launch_bounds__(256) void gemm_bt_k(const ushort* __restrict__ X,
                                                 const ushort* __restrict__ Wt,
                                                 float* __restrict__ Y) {
  __shared__ ushort lds[8192];   // 8KB A + 8KB B
  const int tid = threadIdx.x;
  const int w = tid >> 6, lane = tid & 63;
  const int bm = blockIdx.x, bn = blockIdx.y;
  const int wr = w >> 1, wc = w & 1;

  // staging: 8 wave-instructions each for A and B; wave w issues s=w and s=w+4
  const int s0 = w, s1 = w + 4;
  const int ra = s0 * 16 + (lane >> 2);
  const int rb = s1 * 16 + (lane >> 2);
  const int ga = (lane & 3) ^ ((ra >> 1) & 3);
  const int gb = (lane & 3) ^ ((rb >> 1) & 3);
  const ushort* gA0 = X  + (size_t)(bm * 128 + ra) * 2048 + ga * 8;
  const ushort* gA1 = X  + (size_t)(bm * 128 + rb) * 2048 + gb * 8;
  const ushort* gB0 = Wt + (size_t)(bn * 128 + ra) * 2048 + ga * 8;
  const ushort* gB1 = Wt + (size_t)(bn * 128 + rb) * 2048 + gb * 8;
  ushort* lA0 = &lds[s0 * 512];
  ushort* lA1 = &lds[s1 * 512];
  ushort* lB0 = &lds[4096 + s0 * 512];
  ushort* lB1 = &lds[4096 + s1 * 512];

  // fragment ds_read offsets (ushort units), swizzle-matched
  int offA[4], offB[4];
#pragma unroll
  for (int m = 0; m < 4; ++m) {
    int R = wr * 64 + m * 16 + (lane & 15);
    offA[m] = R * 32 + ((((lane >> 4) ^ ((R >> 1) & 3))) << 3);
    int C = wc * 64 + m * 16 + (lane & 15);
    offB[m] = 4096 + C * 32 + ((((lane >> 4) ^ ((C >> 1) & 3))) << 3);
  }

  f32x4 acc[4][4] = {};

  for (int kk = 0; kk < 64; ++kk) {
    const int ko = kk * 32;
    GLOAD_LDS16(gA0 + ko, lA0);
    GLOAD_LDS16(gA1 + ko, lA1);
    GLOAD_LDS16(gB0 + ko, lB0);
    GLOAD_LDS16(gB1 + ko, lB1);
    __syncthreads();

    bf16x8 a[4], b[4];
#pragma unroll
    for (int m = 0; m < 4; ++m) a[m] = *reinterpret_cast<const bf16x8*>(&lds[offA[m]]);
#pragma unroll
    for (int n = 0; n < 4; ++n) b[n] = *reinterpret_cast<const bf16x8*>(&lds[offB[n]]);
#pragma unroll
    for (int m = 0; m < 4; ++m)
#pragma unroll
      for (int n = 0; n < 4; ++n)
        acc[m][n] = __builtin_amdgcn_mfma_f32_16x16x32_bf16(a[m], b[n], acc[m][n], 0, 0, 0);

    __syncthreads();
  }

  // epilogue: C/D layout col=lane&15, row=(lane>>4)*4+j  [m89-verified]
#pragma unroll
  for (int m = 0; m < 4; ++m) {
    int row0 = bm * 128 + wr * 64 + m * 16 + ((lane >> 4) << 2);
#pragma unroll
    for (int n = 0; n < 4; ++n) {
      int col = bn * 128 + wc * 64 + n * 16 + (lane & 15);
#pragma unroll
      for (int j = 0; j < 4; ++j)
        Y[(size_t)(row0 + j) * 1408 + col] = acc[m][n][j];
    }
  }
}

// ---------- kernel 4: per-token low-rank reconstruction + concat ----------
// Y row: [0,96) a_q(h*6+r) | [96,112) a_k | [112,128) a_v | [128,896) b_q(r*128+d)
//        | [896,1152) b_k | [1152,1408) b_v
// out row (4096): per group g: q_head(2g)[128] q_head(2g+1)[128] k_g[128] v_g[128]
__global__ void recon_k(const float* __restrict__ Y, float* __restrict__ out) {
  __shared__ float L[1408];
  const int t = blockIdx.x, tid = threadIdx.x;
  const float4* src = (const float4*)(Y + (size_t)t * 1408);
  float4* Ld = (float4*)L;
  for (int i = tid; i < 352; i += 256) Ld[i] = src[i];
  __syncthreads();
  float* o = out + (size_t)t * 4096;
#pragma unroll
  for (int i = 0; i < 16; ++i) {
    int p = tid + (i << 8);
    int g = p >> 9, sub = p & 511;
    float val;
    if (sub < 256) {               // q
      int h = (g << 1) + (sub >> 7), d = sub & 127;
      const float* a = L + h * 6;
      const float* b = L + 128 + d;
      val = (a[0] * b[0] + a[1] * b[128] + a[2] * b[256] +
             a[3] * b[384] + a[4] * b[512] + a[5] * b[640]) * (1.0f / 6.0f);
    } else if (sub < 384) {        // k
      int d = sub - 256;
      val = 0.5f * (L[96 + (g << 1)] * L[896 + d] + L[97 + (g << 1)] * L[1024 + d]);
    } else {                       // v
      int d = sub - 384;
      val = 0.5f * (L[112 + (g << 1)] * L[1152 + d] + L[113 + (g << 1)] * L[1280 + d]);
    }
    o[p] = val;
  }
}

// ---------- launch ----------
extern "C" void kernel_launch(void* const* d_in, const int* in_sizes, int n_in,
                              void* d_out, int out_size, void* d_ws, size_t ws_size,
                              hipStream_t stream) {
  const float* x   = (const float*)d_in[0];
  const float* Waq = (const float*)d_in[1];
  const float* Wak = (const float*)d_in[2];
  const float* Wav = (const float*)d_in[3];
  const float* Wbq = (const float*)d_in[4];
  const float* Wbk = (const float*)d_in[5];
  const float* Wbv = (const float*)d_in[6];

  // workspace layout
  ushort* Xbf = (ushort*)d_ws;                                  // 8192*2048*2 = 33,554,432 B
  ushort* Wt  = (ushort*)((char*)d_ws + 33554432);              // 1408*2048*2 =  5,767,168 B
  float*  Y   = (float*) ((char*)d_ws + 39321600);              // 8192*1408*4 = 46,137,344 B
  float*  out = (float*)d_out;

  cast_x_k<<<2048, 256, 0, stream>>>((const float4*)x, (ushort4*)Xbf, 16777216 / 4);
  pack_wt_k<<<dim3(32, 22), 256, 0, stream>>>(Waq, Wak, Wav, Wbq, Wbk, Wbv, Wt);
  gemm_bt_k<<<dim3(64, 11), 256, 0, stream>>>(Xbf, Wt, Y);
  recon_k<<<8192, 256, 0, stream>>>(Y, out);
}

// Round 2
// 274.208 us; speedup vs baseline: 1.1051x; 1.1051x over previous
//
#include <hip/hip_runtime.h>
#include <hip/hip_bf16.h>

// ---------- common ----------
typedef __bf16 bf16x8 __attribute__((ext_vector_type(8)));
typedef float  f32x4  __attribute__((ext_vector_type(4)));

#define GLOAD_LDS16(g, l) \
  __builtin_amdgcn_global_load_lds((const __attribute__((address_space(1))) void*)(g), \
                                   (__attribute__((address_space(3))) void*)(l), 16, 0, 0)

static __device__ __forceinline__ ushort f2bf(float f) {
  union { float f; unsigned u; } x; x.f = f;
  unsigned r = x.u + 0x7fffu + ((x.u >> 16) & 1u);   // RNE
  return (ushort)(r >> 16);
}
static __device__ __forceinline__ float bf2f(ushort u) {
  union { unsigned u; float f; } x; x.u = ((unsigned)u) << 16;
  return x.f;
}

// ---------- kernel 1: cast x fp32 -> bf16 ----------
__global__ void cast_x_k(const float4* __restrict__ in, ushort4* __restrict__ out, int n4) {
  int idx = blockIdx.x * 256 + threadIdx.x;
  int stride = gridDim.x * 256;
  for (int i = idx; i < n4; i += stride) {
    float4 v = in[i];
    ushort4 o;
    o.x = f2bf(v.x); o.y = f2bf(v.y); o.z = f2bf(v.z); o.w = f2bf(v.w);
    out[i] = o;
  }
}

// ---------- kernel 2: pack 6 weights into Wt[1408][2048] bf16 (transposed) ----------
// column map: 0-95 a_q | 96-111 a_k | 112-127 a_v | 128-895 b_q | 896-1151 b_k | 1152-1407 b_v
__global__ void pack_wt_k(const float* __restrict__ W0, const float* __restrict__ W1,
                          const float* __restrict__ W2, const float* __restrict__ W3,
                          const float* __restrict__ W4, const float* __restrict__ W5,
                          ushort* __restrict__ Wt) {
  __shared__ ushort tile[64 * 66];
  const int k0 = blockIdx.x * 64, c0 = blockIdx.y * 64;
  const int tid = threadIdx.x;
#pragma unroll
  for (int i = 0; i < 16; ++i) {
    int idx = tid + i * 256;
    int kl = idx >> 6, cl = idx & 63;
    int c = c0 + cl, k = k0 + kl;
    const float* W; int n, lc;
    if (c < 96)       { W = W0; n = 96;  lc = c; }
    else if (c < 112) { W = W1; n = 16;  lc = c - 96; }
    else if (c < 128) { W = W2; n = 16;  lc = c - 112; }
    else if (c < 896) { W = W3; n = 768; lc = c - 128; }
    else if (c < 1152){ W = W4; n = 256; lc = c - 896; }
    else              { W = W5; n = 256; lc = c - 1152; }
    tile[cl * 66 + kl] = f2bf(W[(size_t)k * n + lc]);
  }
  __syncthreads();
#pragma unroll
  for (int i = 0; i < 16; ++i) {
    int idx = tid + i * 256;
    int cl = idx >> 6, kl = idx & 63;
    Wt[(size_t)(c0 + cl) * 2048 + (k0 + kl)] = tile[cl * 66 + kl];
  }
}

// ---------- kernel 3: GEMM  Y[8192][1408] = Xbf[8192][2048] @ Wt[1408][2048]^T, bf16 out ----
// 128x128 tile, BK=32, 4 waves (2x2), mfma_f32_16x16x32_bf16.
// 2-phase double-buffered LDS: STAGE(next) issued before ds_read+MFMA(cur),
// one vmcnt(0)+barrier (__syncthreads) per K-step.  XCD-chunked 1D swizzle (704%8==0).
__global__ __launch_bounds__(256) void gemm_bt_k(const ushort* __restrict__ X,
                                                 const ushort* __restrict__ Wt,
                                                 ushort* __restrict__ Y) {
  __shared__ ushort lds[2][8192];   // 2 x (8KB A + 8KB B)
  const int tid = threadIdx.x;
  const int w = tid >> 6, lane = tid & 63;
  // XCD-chunked bijective swizzle: grid 704 = 8 * 88
  const int bid = blockIdx.x;
  const int wg = (bid & 7) * 88 + (bid >> 3);
  const int bm = wg & 63, bn = wg >> 6;
  const int wr = w >> 1, wc = w & 1;

  // staging: 8 wave-instructions each for A and B; wave w issues s=w and s=w+4
  const int s0 = w, s1 = w + 4;
  const int ra = s0 * 16 + (lane >> 2);
  const int rb = s1 * 16 + (lane >> 2);
  const int ga = (lane & 3) ^ ((ra >> 1) & 3);
  const int gb = (lane & 3) ^ ((rb >> 1) & 3);
  const ushort* gA0 = X  + (size_t)(bm * 128 + ra) * 2048 + ga * 8;
  const ushort* gA1 = X  + (size_t)(bm * 128 + rb) * 2048 + gb * 8;
  const ushort* gB0 = Wt + (size_t)(bn * 128 + ra) * 2048 + ga * 8;
  const ushort* gB1 = Wt + (size_t)(bn * 128 + rb) * 2048 + gb * 8;
  const int lo0 = s0 * 512, lo1 = s1 * 512;

  // fragment ds_read offsets (ushort units), swizzle-matched
  int offA[4], offB[4];
#pragma unroll
  for (int m = 0; m < 4; ++m) {
    int R = wr * 64 + m * 16 + (lane & 15);
    offA[m] = R * 32 + ((((lane >> 4) ^ ((R >> 1) & 3))) << 3);
    int C = wc * 64 + m * 16 + (lane & 15);
    offB[m] = 4096 + C * 32 + ((((lane >> 4) ^ ((C >> 1) & 3))) << 3);
  }

  // prologue: stage K-step 0 into buf 0
  GLOAD_LDS16(gA0, &lds[0][lo0]);
  GLOAD_LDS16(gA1, &lds[0][lo1]);
  GLOAD_LDS16(gB0, &lds[0][4096 + lo0]);
  GLOAD_LDS16(gB1, &lds[0][4096 + lo1]);
  __syncthreads();

  f32x4 acc[4][4] = {};
  int cur = 0;

  for (int kk = 0; kk < 64; ++kk) {
    if (kk < 63) {                       // issue next-tile loads first (overlap)
      const int ko = (kk + 1) * 32;
      ushort* nb = lds[cur ^ 1];
      GLOAD_LDS16(gA0 + ko, nb + lo0);
      GLOAD_LDS16(gA1 + ko, nb + lo1);
      GLOAD_LDS16(gB0 + ko, nb + 4096 + lo0);
      GLOAD_LDS16(gB1 + ko, nb + 4096 + lo1);
    }
    const ushort* cb = lds[cur];
    bf16x8 a[4], b[4];
#pragma unroll
    for (int m = 0; m < 4; ++m) a[m] = *reinterpret_cast<const bf16x8*>(&cb[offA[m]]);
#pragma unroll
    for (int n = 0; n < 4; ++n) b[n] = *reinterpret_cast<const bf16x8*>(&cb[offB[n]]);
#pragma unroll
    for (int m = 0; m < 4; ++m)
#pragma unroll
      for (int n = 0; n < 4; ++n)
        acc[m][n] = __builtin_amdgcn_mfma_f32_16x16x32_bf16(a[m], b[n], acc[m][n], 0, 0, 0);

    __syncthreads();                      // vmcnt(0)+lgkmcnt(0)+barrier: next buf ready
    cur ^= 1;
  }

  // epilogue: C/D layout col=lane&15, row=(lane>>4)*4+j  [m89-verified]; bf16 store
#pragma unroll
  for (int m = 0; m < 4; ++m) {
    int row0 = bm * 128 + wr * 64 + m * 16 + ((lane >> 4) << 2);
#pragma unroll
    for (int n = 0; n < 4; ++n) {
      int col = bn * 128 + wc * 64 + n * 16 + (lane & 15);
#pragma unroll
      for (int j = 0; j < 4; ++j)
        Y[(size_t)(row0 + j) * 1408 + col] = f2bf(acc[m][n][j]);
    }
  }
}

// ---------- kernel 4: per-token low-rank reconstruction + concat (bf16 Y in, f32 out) ----
// Y row: [0,96) a_q(h*6+r) | [96,112) a_k | [112,128) a_v | [128,896) b_q(r*128+d)
//        | [896,1152) b_k | [1152,1408) b_v
// out row (4096): per group g: q_head(2g)[128] q_head(2g+1)[128] k_g[128] v_g[128]
__global__ void recon_k(const ushort* __restrict__ Y, float4* __restrict__ out) {
  __shared__ float L[1408];
  const int t = blockIdx.x, tid = threadIdx.x;
  const ushort* src = Y + (size_t)t * 1408;
  if (tid < 176) {                        // 176 x 16B = 1408 bf16
    ushort4 v0 = ((const ushort4*)src)[tid * 2];
    ushort4 v1 = ((const ushort4*)src)[tid * 2 + 1];
    float* d = L + tid * 8;
    d[0] = bf2f(v0.x); d[1] = bf2f(v0.y); d[2] = bf2f(v0.z); d[3] = bf2f(v0.w);
    d[4] = bf2f(v1.x); d[5] = bf2f(v1.y); d[6] = bf2f(v1.z); d[7] = bf2f(v1.w);
  }
  __syncthreads();
  float4* o = out + (size_t)t * 1024;
#pragma unroll
  for (int i = 0; i < 4; ++i) {
    int q4 = tid + (i << 8);              // float4 index 0..1023
    int p = q4 << 2;
    int g = p >> 9, sub = p & 511;
    float4 val;
    if (sub < 256) {                      // q
      int h = (g << 1) + (sub >> 7), d = sub & 127;
      const float* a = L + h * 6;
      const float* b = L + 128 + d;
#pragma unroll
      for (int c = 0; c < 4; ++c)
        (&val.x)[c] = (a[0] * b[c] + a[1] * b[128 + c] + a[2] * b[256 + c] +
                       a[3] * b[384 + c] + a[4] * b[512 + c] + a[5] * b[640 + c]) * (1.0f / 6.0f);
    } else if (sub < 384) {               // k
      int d = sub - 256;
      float a0 = L[96 + (g << 1)], a1 = L[97 + (g << 1)];
#pragma unroll
      for (int c = 0; c < 4; ++c)
        (&val.x)[c] = 0.5f * (a0 * L[896 + d + c] + a1 * L[1024 + d + c]);
    } else {                              // v
      int d = sub - 384;
      float a0 = L[112 + (g << 1)], a1 = L[113 + (g << 1)];
#pragma unroll
      for (int c = 0; c < 4; ++c)
        (&val.x)[c] = 0.5f * (a0 * L[1152 + d + c] + a1 * L[1280 + d + c]);
    }
    o[q4] = val;
  }
}

// ---------- launch ----------
extern "C" void kernel_launch(void* const* d_in, const int* in_sizes, int n_in,
                              void* d_out, int out_size, void* d_ws, size_t ws_size,
                              hipStream_t stream) {
  const float* x   = (const float*)d_in[0];
  const float* Waq = (const float*)d_in[1];
  const float* Wak = (const float*)d_in[2];
  const float* Wav = (const float*)d_in[3];
  const float* Wbq = (const float*)d_in[4];
  const float* Wbk = (const float*)d_in[5];
  const float* Wbv = (const float*)d_in[6];

  // workspace layout
  ushort* Xbf = (ushort*)d_ws;                                  // 8192*2048*2 = 33,554,432 B
  ushort* Wt  = (ushort*)((char*)d_ws + 33554432);              // 1408*2048*2 =  5,767,168 B
  ushort* Y   = (ushort*)((char*)d_ws + 39321600);              // 8192*1408*2 = 23,068,672 B
  float*  out = (float*)d_out;

  cast_x_k<<<2048, 256, 0, stream>>>((const float4*)x, (ushort4*)Xbf, 16777216 / 4);
  pack_wt_k<<<dim3(32, 22), 256, 0, stream>>>(Waq, Wak, Wav, Wbq, Wbk, Wbv, Wt);
  gemm_bt_k<<<704, 256, 0, stream>>>(Xbf, Wt, Y);
  recon_k<<<8192, 256, 0, stream>>>(Y, (float4*)out);
}

// Round 3
// 271.742 us; speedup vs baseline: 1.1151x; 1.0091x over previous
//
#include <hip/hip_runtime.h>
#include <hip/hip_bf16.h>

// ---------- common ----------
typedef __bf16 bf16x8 __attribute__((ext_vector_type(8)));
typedef float  f32x4  __attribute__((ext_vector_type(4)));

#define GLOAD_LDS16(g, l) \
  __builtin_amdgcn_global_load_lds((const __attribute__((address_space(1))) void*)(g), \
                                   (__attribute__((address_space(3))) void*)(l), 16, 0, 0)

static __device__ __forceinline__ ushort f2bf(float f) {
  union { float f; unsigned u; } x; x.f = f;
  unsigned r = x.u + 0x7fffu + ((x.u >> 16) & 1u);   // RNE
  return (ushort)(r >> 16);
}
static __device__ __forceinline__ float bf2f(ushort u) {
  union { unsigned u; float f; } x; x.u = ((unsigned)u) << 16;
  return x.f;
}

// ---------- kernel 1: cast x fp32 -> bf16 ----------
__global__ void cast_x_k(const float4* __restrict__ in, ushort4* __restrict__ out, int n4) {
  int idx = blockIdx.x * 256 + threadIdx.x;
  int stride = gridDim.x * 256;
  for (int i = idx; i < n4; i += stride) {
    float4 v = in[i];
    ushort4 o;
    o.x = f2bf(v.x); o.y = f2bf(v.y); o.z = f2bf(v.z); o.w = f2bf(v.w);
    out[i] = o;
  }
}

// ---------- kernel 2: pack 6 weights into Wt[1408][2048] bf16 (transposed) ----------
// column map: 0-95 a_q | 96-111 a_k | 112-127 a_v | 128-895 b_q | 896-1151 b_k | 1152-1407 b_v
__global__ void pack_wt_k(const float* __restrict__ W0, const float* __restrict__ W1,
                          const float* __restrict__ W2, const float* __restrict__ W3,
                          const float* __restrict__ W4, const float* __restrict__ W5,
                          ushort* __restrict__ Wt) {
  __shared__ ushort tile[64 * 66];
  const int k0 = blockIdx.x * 64, c0 = blockIdx.y * 64;
  const int tid = threadIdx.x;
#pragma unroll
  for (int i = 0; i < 16; ++i) {
    int idx = tid + i * 256;
    int kl = idx >> 6, cl = idx & 63;
    int c = c0 + cl, k = k0 + kl;
    const float* W; int n, lc;
    if (c < 96)       { W = W0; n = 96;  lc = c; }
    else if (c < 112) { W = W1; n = 16;  lc = c - 96; }
    else if (c < 128) { W = W2; n = 16;  lc = c - 112; }
    else if (c < 896) { W = W3; n = 768; lc = c - 128; }
    else if (c < 1152){ W = W4; n = 256; lc = c - 896; }
    else              { W = W5; n = 256; lc = c - 1152; }
    tile[cl * 66 + kl] = f2bf(W[(size_t)k * n + lc]);
  }
  __syncthreads();
#pragma unroll
  for (int i = 0; i < 16; ++i) {
    int idx = tid + i * 256;
    int cl = idx >> 6, kl = idx & 63;
    Wt[(size_t)(c0 + cl) * 2048 + (k0 + kl)] = tile[cl * 66 + kl];
  }
}

// ---------- kernel 3: GEMM  Y[8192][1408] = Xbf[8192][2048] @ Wt[1408][2048]^T, bf16 out ----
// 128x128 tile, BK=32, 4 waves (2x2), mfma_f32_16x16x32_bf16.
// 3-buffer pipeline with COUNTED vmcnt (T3+T4): tile t waited with vmcnt(8)
// (= only the tile staged 3 iters ago), never drained to 0 in the main loop.
// Raw s_barrier + explicit asm waitcnts ("memory" clobber keeps ds_reads below
// the data-ready point).  XCD-chunked 1D swizzle (704 = 8*88, bijective).
__global__ __launch_bounds__(256) void gemm_bt_k(const ushort* __restrict__ X,
                                                 const ushort* __restrict__ Wt,
                                                 ushort* __restrict__ Y) {
  __shared__ ushort lds[3 * 8192];   // 3 x (8KB A + 8KB B) = 48 KB
  const int tid = threadIdx.x;
  const int w = tid >> 6, lane = tid & 63;
  const int bid = blockIdx.x;
  const int wg = (bid & 7) * 88 + (bid >> 3);
  const int bm = wg & 63, bn = wg >> 6;
  const int wr = w >> 1, wc = w & 1;

  // staging: 8 wave-instructions each for A and B; wave w issues s=w and s=w+4
  const int s0 = w, s1 = w + 4;
  const int ra = s0 * 16 + (lane >> 2);
  const int rb = s1 * 16 + (lane >> 2);
  const int ga = (lane & 3) ^ ((ra >> 1) & 3);
  const int gb = (lane & 3) ^ ((rb >> 1) & 3);
  const ushort* gA0 = X  + (size_t)(bm * 128 + ra) * 2048 + ga * 8;
  const ushort* gA1 = X  + (size_t)(bm * 128 + rb) * 2048 + gb * 8;
  const ushort* gB0 = Wt + (size_t)(bn * 128 + ra) * 2048 + ga * 8;
  const ushort* gB1 = Wt + (size_t)(bn * 128 + rb) * 2048 + gb * 8;
  const int lo0 = s0 * 512, lo1 = s1 * 512;

  // fragment ds_read offsets (ushort units), swizzle-matched
  int offA[4], offB[4];
#pragma unroll
  for (int m = 0; m < 4; ++m) {
    int R = wr * 64 + m * 16 + (lane & 15);
    offA[m] = R * 32 + ((((lane >> 4) ^ ((R >> 1) & 3))) << 3);
    int C = wc * 64 + m * 16 + (lane & 15);
    offB[m] = 4096 + C * 32 + ((((lane >> 4) ^ ((C >> 1) & 3))) << 3);
  }

  f32x4 acc[4][4] = {};

#define STAGE(bufi, kstep) do { \
    ushort* nb = &lds[(bufi) * 8192]; \
    const int _ko = (kstep) * 32; \
    GLOAD_LDS16(gA0 + _ko, nb + lo0); \
    GLOAD_LDS16(gA1 + _ko, nb + lo1); \
    GLOAD_LDS16(gB0 + _ko, nb + 4096 + lo0); \
    GLOAD_LDS16(gB1 + _ko, nb + 4096 + lo1); \
  } while (0)

#define COMPUTE(bufi) do { \
    const ushort* cb = &lds[(bufi) * 8192]; \
    bf16x8 a[4], b[4]; \
    _Pragma("unroll") \
    for (int m = 0; m < 4; ++m) a[m] = *reinterpret_cast<const bf16x8*>(&cb[offA[m]]); \
    _Pragma("unroll") \
    for (int n = 0; n < 4; ++n) b[n] = *reinterpret_cast<const bf16x8*>(&cb[offB[n]]); \
    _Pragma("unroll") \
    for (int m = 0; m < 4; ++m) \
      _Pragma("unroll") \
      for (int n = 0; n < 4; ++n) \
        acc[m][n] = __builtin_amdgcn_mfma_f32_16x16x32_bf16(a[m], b[n], acc[m][n], 0, 0, 0); \
  } while (0)

#define WAITV(n) asm volatile("s_waitcnt vmcnt(" #n ")" ::: "memory")
#define WAITL()  asm volatile("s_waitcnt lgkmcnt(0)" ::: "memory")
#define BAR()    __builtin_amdgcn_s_barrier()

  // prologue: stage K-steps 0,1,2 into bufs 0,1,2 (12 loads in flight/wave)
  STAGE(0, 0); STAGE(1, 1); STAGE(2, 2);

  // main loop: t = 0..59 (20 x 3 unrolled), steady-state vmcnt(8)
#pragma unroll 1
  for (int t = 0; t < 60; t += 3) {
    WAITV(8); BAR();
    COMPUTE(0);
    WAITL(); BAR();
    STAGE(0, t + 3);

    WAITV(8); BAR();
    COMPUTE(1);
    WAITL(); BAR();
    STAGE(1, t + 4);

    WAITV(8); BAR();
    COMPUTE(2);
    WAITL(); BAR();
    STAGE(2, t + 5);
  }
  // t=60: in flight {60,61,62}; stage 63 into buf0 after compute
  WAITV(8); BAR();
  COMPUTE(0);
  WAITL(); BAR();
  STAGE(0, 63);
  // t=61: in flight {61,62,63}
  WAITV(8); BAR();
  COMPUTE(1);
  // t=62: in flight {62,63}
  WAITV(4); BAR();
  COMPUTE(2);
  // t=63: in flight {63}
  WAITV(0); BAR();
  COMPUTE(0);

#undef STAGE
#undef COMPUTE
#undef WAITV
#undef WAITL
#undef BAR

  // epilogue: C/D layout col=lane&15, row=(lane>>4)*4+j  [m89-verified]; bf16 store
#pragma unroll
  for (int m = 0; m < 4; ++m) {
    int row0 = bm * 128 + wr * 64 + m * 16 + ((lane >> 4) << 2);
#pragma unroll
    for (int n = 0; n < 4; ++n) {
      int col = bn * 128 + wc * 64 + n * 16 + (lane & 15);
#pragma unroll
      for (int j = 0; j < 4; ++j)
        Y[(size_t)(row0 + j) * 1408 + col] = f2bf(acc[m][n][j]);
    }
  }
}

// ---------- kernel 4: per-token low-rank reconstruction + concat (bf16 Y in, f32 out) ----
// Y row: [0,96) a_q(h*6+r) | [96,112) a_k | [112,128) a_v | [128,896) b_q(r*128+d)
//        | [896,1152) b_k | [1152,1408) b_v
// out row (4096): per group g: q_head(2g)[128] q_head(2g+1)[128] k_g[128] v_g[128]
__global__ void recon_k(const ushort* __restrict__ Y, float4* __restrict__ out) {
  __shared__ float L[1408];
  const int t = blockIdx.x, tid = threadIdx.x;
  const ushort* src = Y + (size_t)t * 1408;
  if (tid < 176) {                        // 176 x 16B = 1408 bf16
    ushort4 v0 = ((const ushort4*)src)[tid * 2];
    ushort4 v1 = ((const ushort4*)src)[tid * 2 + 1];
    float* d = L + tid * 8;
    d[0] = bf2f(v0.x); d[1] = bf2f(v0.y); d[2] = bf2f(v0.z); d[3] = bf2f(v0.w);
    d[4] = bf2f(v1.x); d[5] = bf2f(v1.y); d[6] = bf2f(v1.z); d[7] = bf2f(v1.w);
  }
  __syncthreads();
  float4* o = out + (size_t)t * 1024;
#pragma unroll
  for (int i = 0; i < 4; ++i) {
    int q4 = tid + (i << 8);              // float4 index 0..1023
    int p = q4 << 2;
    int g = p >> 9, sub = p & 511;
    float4 val;
    if (sub < 256) {                      // q
      int h = (g << 1) + (sub >> 7), d = sub & 127;
      const float* a = L + h * 6;
      const float* b = L + 128 + d;
#pragma unroll
      for (int c = 0; c < 4; ++c)
        (&val.x)[c] = (a[0] * b[c] + a[1] * b[128 + c] + a[2] * b[256 + c] +
                       a[3] * b[384 + c] + a[4] * b[512 + c] + a[5] * b[640 + c]) * (1.0f / 6.0f);
    } else if (sub < 384) {               // k
      int d = sub - 256;
      float a0 = L[96 + (g << 1)], a1 = L[97 + (g << 1)];
#pragma unroll
      for (int c = 0; c < 4; ++c)
        (&val.x)[c] = 0.5f * (a0 * L[896 + d + c] + a1 * L[1024 + d + c]);
    } else {                              // v
      int d = sub - 384;
      float a0 = L[112 + (g << 1)], a1 = L[113 + (g << 1)];
#pragma unroll
      for (int c = 0; c < 4; ++c)
        (&val.x)[c] = 0.5f * (a0 * L[1152 + d + c] + a1 * L[1280 + d + c]);
    }
    o[q4] = val;
  }
}

// ---------- launch ----------
extern "C" void kernel_launch(void* const* d_in, const int* in_sizes, int n_in,
                              void* d_out, int out_size, void* d_ws, size_t ws_size,
                              hipStream_t stream) {
  const float* x   = (const float*)d_in[0];
  const float* Waq = (const float*)d_in[1];
  const float* Wak = (const float*)d_in[2];
  const float* Wav = (const float*)d_in[3];
  const float* Wbq = (const float*)d_in[4];
  const float* Wbk = (const float*)d_in[5];
  const float* Wbv = (const float*)d_in[6];

  // workspace layout
  ushort* Xbf = (ushort*)d_ws;                                  // 8192*2048*2 = 33,554,432 B
  ushort* Wt  = (ushort*)((char*)d_ws + 33554432);              // 1408*2048*2 =  5,767,168 B
  ushort* Y   = (ushort*)((char*)d_ws + 39321600);              // 8192*1408*2 = 23,068,672 B
  float*  out = (float*)d_out;

  cast_x_k<<<2048, 256, 0, stream>>>((const float4*)x, (ushort4*)Xbf, 16777216 / 4);
  pack_wt_k<<<dim3(32, 22), 256, 0, stream>>>(Waq, Wak, Wav, Wbq, Wbk, Wbv, Wt);
  gemm_bt_k<<<704, 256, 0, stream>>>(Xbf, Wt, Y);
  recon_k<<<8192, 256, 0, stream>>>(Y, (float4*)out);
}